// Round 1
// baseline (1452.709 us; speedup 1.0000x reference)
//
#include <hip/hip_runtime.h>

typedef __attribute__((ext_vector_type(8))) short short8;
typedef __attribute__((ext_vector_type(4))) float f32x4;
typedef unsigned short u16;

#define NEG_BIG (-1e30f)

__device__ __forceinline__ u16 f2b(float x) {
  unsigned u = __float_as_uint(x);
  u += 0x7FFFu + ((u >> 16) & 1u);   // round-to-nearest-even bf16
  return (u16)(u >> 16);
}

// ---------------------------------------------------------------- casts ----
__global__ __launch_bounds__(256) void cast_f32_bf16(const float* __restrict__ src,
                                                     u16* __restrict__ dst, int n4) {
  int i = blockIdx.x * 256 + threadIdx.x;
  if (i >= n4) return;
  float4 v = ((const float4*)src)[i];
  uint2 pv;
  pv.x = (unsigned)f2b(v.x) | ((unsigned)f2b(v.y) << 16);
  pv.y = (unsigned)f2b(v.z) | ((unsigned)f2b(v.w) << 16);
  ((uint2*)dst)[i] = pv;
}

// k_cache [B,H,2048,128] f32 -> Kb [B,H,4096,128] bf16 (t in [0,2048))
__global__ __launch_bounds__(256) void cast_kcache(const float* __restrict__ src,
                                                   u16* __restrict__ dst) {
  int i = blockIdx.x * 256 + threadIdx.x;   // float4 units, < 2097152
  if (i >= 2097152) return;
  int bh  = i >> 16;        // / (2048*128/4)
  int rem = i & 65535;
  float4 v = ((const float4*)src)[i];
  uint2 pv;
  pv.x = (unsigned)f2b(v.x) | ((unsigned)f2b(v.y) << 16);
  pv.y = (unsigned)f2b(v.z) | ((unsigned)f2b(v.w) << 16);
  ((uint2*)dst)[(size_t)bh * 131072 + rem] = pv;
}

// v_cache [B,H,2048,128] f32 -> Vt [B,H,128,4096] bf16 (t in [0,2048))
__global__ __launch_bounds__(256) void transpose_v(const float* __restrict__ src,
                                                   u16* __restrict__ dst) {
  __shared__ u16 lds[128 * 68];
  const int tid = threadIdx.x;
  const int bh = blockIdx.y;
  const int t0 = blockIdx.x * 64;
#pragma unroll
  for (int p = 0; p < 8; p++) {
    int idx = p * 256 + tid;            // 0..2047
    int t = idx >> 5;                   // 0..63
    int d4 = (idx & 31) * 4;
    float4 v = *(const float4*)&src[(((size_t)bh * 2048) + t0 + t) * 128 + d4];
    lds[(d4 + 0) * 68 + t] = f2b(v.x);
    lds[(d4 + 1) * 68 + t] = f2b(v.y);
    lds[(d4 + 2) * 68 + t] = f2b(v.z);
    lds[(d4 + 3) * 68 + t] = f2b(v.w);
  }
  __syncthreads();
  const int d = tid >> 1;
  const int th = (tid & 1) * 32;
  size_t obase = ((size_t)bh * 128 + d) * 4096 + t0 + th;
#pragma unroll
  for (int jb = 0; jb < 4; jb++) {
    const u16* lp = &lds[d * 68 + th + jb * 8];
    uint4 pv;
    pv.x = (unsigned)lp[0] | ((unsigned)lp[1] << 16);
    pv.y = (unsigned)lp[2] | ((unsigned)lp[3] << 16);
    pv.z = (unsigned)lp[4] | ((unsigned)lp[5] << 16);
    pv.w = (unsigned)lp[6] | ((unsigned)lp[7] << 16);
    *(uint4*)&dst[obase + jb * 8] = pv;
  }
}

// ---------------------------------------------------------------- GEMM -----
// C[m,n] = sum_k A[m*2048+k] * Bm[n*2048+k]   (M=4096, N=2048, K=2048)
// isOut=0: z=0/1/2 -> scatter into Qb / Kb(t=2048+s) / Vt(t=2048+s)
// isOut=1: write fp32 Cout row-major
#define LDA 40
__global__ __launch_bounds__(256) void gemm_bt(
    const u16* __restrict__ A, const u16* __restrict__ Bq,
    const u16* __restrict__ Bk, const u16* __restrict__ Bv,
    u16* __restrict__ Qb, u16* __restrict__ Kb, u16* __restrict__ Vt,
    float* __restrict__ Cout, int isOut) {
  __shared__ u16 As[128 * LDA];
  __shared__ u16 Bs[128 * LDA];
  const int tid = threadIdx.x;
  const int lane = tid & 63, w = tid >> 6;
  const int quad = lane >> 4, lm = lane & 15;
  const int n0 = blockIdx.x * 128, m0 = blockIdx.y * 128;
  const int z = blockIdx.z;
  const u16* __restrict__ Bm = isOut ? Bq : (z == 0 ? Bq : (z == 1 ? Bk : Bv));
  const int wm = (w & 1) * 64, wn = (w >> 1) * 64;

  f32x4 acc[4][4];
#pragma unroll
  for (int i = 0; i < 4; i++)
#pragma unroll
    for (int j = 0; j < 4; j++) acc[i][j] = (f32x4){0.f, 0.f, 0.f, 0.f};

  for (int k0 = 0; k0 < 2048; k0 += 32) {
    __syncthreads();
#pragma unroll
    for (int p = 0; p < 2; p++) {
      int idx = p * 256 + tid;          // 0..511
      int row = idx >> 2;               // 0..127
      int col = (idx & 3) * 8;          // 0/8/16/24
      *(uint4*)&As[row * LDA + col] = *(const uint4*)&A[(size_t)(m0 + row) * 2048 + k0 + col];
      *(uint4*)&Bs[row * LDA + col] = *(const uint4*)&Bm[(size_t)(n0 + row) * 2048 + k0 + col];
    }
    __syncthreads();
    short8 af[4], bf[4];
#pragma unroll
    for (int i = 0; i < 4; i++) af[i] = *(const short8*)&As[(wm + i * 16 + lm) * LDA + quad * 8];
#pragma unroll
    for (int j = 0; j < 4; j++) bf[j] = *(const short8*)&Bs[(wn + j * 16 + lm) * LDA + quad * 8];
#pragma unroll
    for (int i = 0; i < 4; i++)
#pragma unroll
      for (int j = 0; j < 4; j++)
        acc[i][j] = __builtin_amdgcn_mfma_f32_16x16x32_bf16(af[i], bf[j], acc[i][j], 0, 0, 0);
  }

  if (isOut) {
#pragma unroll
    for (int i = 0; i < 4; i++)
#pragma unroll
      for (int j = 0; j < 4; j++) {
        int mrow = m0 + wm + i * 16 + quad * 4;
        int ncol = n0 + wn + j * 16 + lm;
#pragma unroll
        for (int r = 0; r < 4; r++)
          Cout[(size_t)(mrow + r) * 2048 + ncol] = acc[i][j][r];
      }
  } else {
#pragma unroll
    for (int i = 0; i < 4; i++)
#pragma unroll
      for (int j = 0; j < 4; j++) {
        int mbase = m0 + wm + i * 16 + quad * 4;
        int n = n0 + wn + j * 16 + lm;
        int b = mbase >> 11;            // all 4 r share b (4-aligned base)
        int s = mbase & 2047;
        int h = n >> 7, hd = n & 127;
        if (z == 0) {
#pragma unroll
          for (int r = 0; r < 4; r++)
            Qb[((size_t)(b * 16 + h) * 2048 + s + r) * 128 + hd] = f2b(acc[i][j][r]);
        } else if (z == 1) {
#pragma unroll
          for (int r = 0; r < 4; r++)
            Kb[((size_t)(b * 16 + h) * 4096 + 2048 + s + r) * 128 + hd] = f2b(acc[i][j][r]);
        } else {
          unsigned long long pv = (unsigned long long)f2b(acc[i][j][0]) |
                                  ((unsigned long long)f2b(acc[i][j][1]) << 16) |
                                  ((unsigned long long)f2b(acc[i][j][2]) << 32) |
                                  ((unsigned long long)f2b(acc[i][j][3]) << 48);
          *(unsigned long long*)&Vt[((size_t)(b * 16 + h) * 128 + hd) * 4096 + 2048 + s] = pv;
        }
      }
  }
}

// ------------------------------------------------------------ attention ----
// Qb [B,H,2048,128], Kb [B,H,4096,128], Vt [B,H,128,4096] (all bf16)
// out attnb [B*S, D] bf16 (row = b*2048+s, col = h*128+hd)
#define PSTR 136
__global__ __launch_bounds__(256) void attn_kernel(
    const u16* __restrict__ Qb, const u16* __restrict__ Kb,
    const u16* __restrict__ Vt, u16* __restrict__ attnb) {
  __shared__ u16 Plds[4 * 16 * PSTR];
  const int tid = threadIdx.x;
  const int lane = tid & 63, w = tid >> 6;
  const int quad = lane >> 4, lm = lane & 15;
  const int s0 = blockIdx.x * 64;
  const int bh = blockIdx.y;
  const int b = bh >> 4, h = bh & 15;
  const u16* __restrict__ Qp = Qb + (size_t)bh * 2048 * 128;
  const u16* __restrict__ Kp = Kb + (size_t)bh * 4096 * 128;
  const u16* __restrict__ Vp = Vt + (size_t)bh * 128 * 4096;
  const int srow = s0 + w * 16;          // this wave's 16 query rows
  u16* __restrict__ myP = &Plds[w * 16 * PSTR];

  short8 qf[4];
#pragma unroll
  for (int c = 0; c < 4; c++)
    qf[c] = *(const short8*)&Qp[(size_t)(srow + lm) * 128 + c * 32 + quad * 8];

  float m_i[4], l_i[4];
  f32x4 oacc[8];
#pragma unroll
  for (int r = 0; r < 4; r++) { m_i[r] = NEG_BIG; l_i[r] = 0.f; }
#pragma unroll
  for (int n = 0; n < 8; n++) oacc[n] = (f32x4){0.f, 0.f, 0.f, 0.f};

  const float scale = 0.08838834764831845f;  // 1/sqrt(128)
  const int ntiles = (2048 + s0 + 63) / 128 + 1;

  for (int tile = 0; tile < ntiles; tile++) {
    const int j0 = tile * 128;
    // ---- S = Q K^T (fragments straight from global; L2-resident) ----
    f32x4 sacc[8];
#pragma unroll
    for (int t = 0; t < 8; t++) sacc[t] = (f32x4){0.f, 0.f, 0.f, 0.f};
#pragma unroll
    for (int c = 0; c < 4; c++)
#pragma unroll
      for (int t = 0; t < 8; t++) {
        short8 kf = *(const short8*)&Kp[(size_t)(j0 + t * 16 + lm) * 128 + c * 32 + quad * 8];
        sacc[t] = __builtin_amdgcn_mfma_f32_16x16x32_bf16(qf[c], kf, sacc[t], 0, 0, 0);
      }
    // ---- scale + causal mask + row max ----
    float tm[4] = {NEG_BIG, NEG_BIG, NEG_BIG, NEG_BIG};
#pragma unroll
    for (int t = 0; t < 8; t++)
#pragma unroll
      for (int r = 0; r < 4; r++) {
        float sv = sacc[t][r] * scale;
        int row = srow + quad * 4 + r;
        if (j0 + t * 16 + lm > 2048 + row) sv = NEG_BIG;
        sacc[t][r] = sv;
        tm[r] = fmaxf(tm[r], sv);
      }
#pragma unroll
    for (int off = 8; off >= 1; off >>= 1)
#pragma unroll
      for (int r = 0; r < 4; r++) tm[r] = fmaxf(tm[r], __shfl_xor(tm[r], off, 64));
    // ---- online softmax update ----
    float alpha[4], ts[4] = {0.f, 0.f, 0.f, 0.f};
#pragma unroll
    for (int r = 0; r < 4; r++) {
      float mn = fmaxf(m_i[r], tm[r]);
      alpha[r] = __expf(m_i[r] - mn);
      m_i[r] = mn;
    }
#pragma unroll
    for (int t = 0; t < 8; t++)
#pragma unroll
      for (int r = 0; r < 4; r++) {
        float p = __expf(sacc[t][r] - m_i[r]);
        ts[r] += p;
        myP[(quad * 4 + r) * PSTR + t * 16 + lm] = f2b(p);  // C-layout -> LDS
      }
#pragma unroll
    for (int off = 8; off >= 1; off >>= 1)
#pragma unroll
      for (int r = 0; r < 4; r++) ts[r] += __shfl_xor(ts[r], off, 64);
#pragma unroll
    for (int r = 0; r < 4; r++) l_i[r] = l_i[r] * alpha[r] + ts[r];
#pragma unroll
    for (int n = 0; n < 8; n++)
#pragma unroll
      for (int r = 0; r < 4; r++) oacc[n][r] *= alpha[r];
    __syncthreads();   // P visible (lgkmcnt(0) fence)
    // ---- O += P V  (P from LDS in A-layout, V^T rows from global) ----
    short8 pf[4];
#pragma unroll
    for (int c = 0; c < 4; c++)
      pf[c] = *(const short8*)&myP[lm * PSTR + c * 32 + quad * 8];
#pragma unroll
    for (int c = 0; c < 4; c++)
#pragma unroll
      for (int n = 0; n < 8; n++) {
        short8 vf = *(const short8*)&Vp[(size_t)(n * 16 + lm) * 4096 + j0 + c * 32 + quad * 8];
        oacc[n] = __builtin_amdgcn_mfma_f32_16x16x32_bf16(pf[c], vf, oacc[n], 0, 0, 0);
      }
    __syncthreads();   // WAR: P reads done before next tile rewrites
  }
  // ---- epilogue: O / l -> attnb ----
#pragma unroll
  for (int r = 0; r < 4; r++) {
    float inv = 1.0f / l_i[r];
    int row = srow + quad * 4 + r;
#pragma unroll
    for (int n = 0; n < 8; n++)
      attnb[((size_t)b * 2048 + row) * 2048 + h * 128 + n * 16 + lm] = f2b(oacc[n][r] * inv);
  }
}

// ---------------------------------------------------------------- launch ---
extern "C" void kernel_launch(void* const* d_in, const int* in_sizes, int n_in,
                              void* d_out, int out_size, void* d_ws, size_t ws_size,
                              hipStream_t stream) {
  const float* hs = (const float*)d_in[0];
  const float* Wq = (const float*)d_in[1];
  const float* Wk = (const float*)d_in[2];
  const float* Wv = (const float*)d_in[3];
  const float* Wo = (const float*)d_in[4];
  const float* kc = (const float*)d_in[5];
  const float* vc = (const float*)d_in[6];
  // d_in[7] = attention_mask: deterministically causal, applied analytically.
  float* out = (float*)d_out;
  if (ws_size < (size_t)134217728) return;  // need 128 MiB

  char* ws = (char*)d_ws;
  u16* Xb  = (u16*)(ws);                 // 16 MiB  [4096][2048] bf16 (reused as attnb)
  u16* Wqb = (u16*)(ws + 16777216);      // 4 x 8 MiB
  u16* Wkb = Wqb + 4194304;
  u16* Wvb = Wqb + 8388608;
  u16* Wob = Wqb + 12582912;
  u16* Kb  = (u16*)(ws + 50331648);      // 32 MiB  [B,H,4096,128]
  u16* Vt  = (u16*)(ws + 83886080);      // 32 MiB  [B,H,128,4096]
  u16* Qb  = (u16*)(ws + 117440512);     // 16 MiB  [B,H,2048,128]
  u16* attnb = Xb;

  cast_f32_bf16<<<8192, 256, 0, stream>>>(hs, Xb, 2097152);
  cast_f32_bf16<<<4096, 256, 0, stream>>>(Wq, Wqb, 1048576);
  cast_f32_bf16<<<4096, 256, 0, stream>>>(Wk, Wkb, 1048576);
  cast_f32_bf16<<<4096, 256, 0, stream>>>(Wv, Wvb, 1048576);
  cast_f32_bf16<<<4096, 256, 0, stream>>>(Wo, Wob, 1048576);
  cast_kcache<<<8192, 256, 0, stream>>>(kc, Kb);
  transpose_v<<<dim3(32, 32), 256, 0, stream>>>(vc, Vt);
  gemm_bt<<<dim3(16, 32, 3), 256, 0, stream>>>(Xb, Wqb, Wkb, Wvb, Qb, Kb, Vt, nullptr, 0);
  attn_kernel<<<dim3(32, 32), 256, 0, stream>>>(Qb, Kb, Vt, attnb);
  gemm_bt<<<dim3(16, 32, 1), 256, 0, stream>>>(attnb, Wob, nullptr, nullptr,
                                               nullptr, nullptr, nullptr, out, 1);
}

// Round 2
// 718.767 us; speedup vs baseline: 2.0211x; 2.0211x over previous
//
#include <hip/hip_runtime.h>

typedef __attribute__((ext_vector_type(8))) short short8;
typedef __attribute__((ext_vector_type(4))) float f32x4;
typedef unsigned short u16;
typedef unsigned long long u64;

#define NEG_BIG (-1e30f)

__device__ __forceinline__ u16 f2b(float x) {
  unsigned u = __float_as_uint(x);
  u += 0x7FFFu + ((u >> 16) & 1u);   // round-to-nearest-even bf16
  return (u16)(u >> 16);
}

__device__ __forceinline__ void gl_lds16(const u16* g, u16* l) {
  __builtin_amdgcn_global_load_lds(
      (const __attribute__((address_space(1))) unsigned int*)(const void*)g,
      (__attribute__((address_space(3))) unsigned int*)(void*)l, 16, 0, 0);
}

// ---------------------------------------------------------------- casts ----
__global__ __launch_bounds__(256) void cast_f32_bf16(const float* __restrict__ src,
                                                     u16* __restrict__ dst, int n4) {
  int i = blockIdx.x * 256 + threadIdx.x;
  if (i >= n4) return;
  float4 v = ((const float4*)src)[i];
  uint2 pv;
  pv.x = (unsigned)f2b(v.x) | ((unsigned)f2b(v.y) << 16);
  pv.y = (unsigned)f2b(v.z) | ((unsigned)f2b(v.w) << 16);
  ((uint2*)dst)[i] = pv;
}

// k_cache [B,H,2048,128] f32 -> Kb [B,H,4096,128] bf16 (t in [0,2048))
__global__ __launch_bounds__(256) void cast_kcache(const float* __restrict__ src,
                                                   u16* __restrict__ dst) {
  int i = blockIdx.x * 256 + threadIdx.x;   // float4 units, < 2097152
  if (i >= 2097152) return;
  int bh  = i >> 16;
  int rem = i & 65535;
  float4 v = ((const float4*)src)[i];
  uint2 pv;
  pv.x = (unsigned)f2b(v.x) | ((unsigned)f2b(v.y) << 16);
  pv.y = (unsigned)f2b(v.z) | ((unsigned)f2b(v.w) << 16);
  ((uint2*)dst)[(size_t)bh * 131072 + rem] = pv;
}

// v_cache [B,H,2048,128] f32 -> Vt [B,H,128,4096] bf16 (t in [0,2048))
__global__ __launch_bounds__(256) void transpose_v(const float* __restrict__ src,
                                                   u16* __restrict__ dst) {
  __shared__ u16 lds[128 * 68];
  const int tid = threadIdx.x;
  const int bh = blockIdx.y;
  const int t0 = blockIdx.x * 64;
#pragma unroll
  for (int p = 0; p < 8; p++) {
    int idx = p * 256 + tid;
    int t = idx >> 5;
    int d4 = (idx & 31) * 4;
    float4 v = *(const float4*)&src[(((size_t)bh * 2048) + t0 + t) * 128 + d4];
    lds[(d4 + 0) * 68 + t] = f2b(v.x);
    lds[(d4 + 1) * 68 + t] = f2b(v.y);
    lds[(d4 + 2) * 68 + t] = f2b(v.z);
    lds[(d4 + 3) * 68 + t] = f2b(v.w);
  }
  __syncthreads();
  const int d = tid >> 1;
  const int th = (tid & 1) * 32;
  size_t obase = ((size_t)bh * 128 + d) * 4096 + t0 + th;
#pragma unroll
  for (int jb = 0; jb < 4; jb++) {
    const u16* lp = &lds[d * 68 + th + jb * 8];
    uint4 pv;
    pv.x = (unsigned)lp[0] | ((unsigned)lp[1] << 16);
    pv.y = (unsigned)lp[2] | ((unsigned)lp[3] << 16);
    pv.z = (unsigned)lp[4] | ((unsigned)lp[5] << 16);
    pv.w = (unsigned)lp[6] | ((unsigned)lp[7] << 16);
    *(uint4*)&dst[obase + jb * 8] = pv;
  }
}

// ---------------------------------------------------------------- GEMM -----
#define LDA 40
__global__ __launch_bounds__(256) void gemm_bt(
    const u16* __restrict__ A, const u16* __restrict__ Bq,
    const u16* __restrict__ Bk, const u16* __restrict__ Bv,
    u16* __restrict__ Qb, u16* __restrict__ Kb, u16* __restrict__ Vt,
    float* __restrict__ Cout, int isOut) {
  __shared__ u16 As[128 * LDA];
  __shared__ u16 Bs[128 * LDA];
  const int tid = threadIdx.x;
  const int lane = tid & 63, w = tid >> 6;
  const int quad = lane >> 4, lm = lane & 15;
  const int n0 = blockIdx.x * 128, m0 = blockIdx.y * 128;
  const int z = blockIdx.z;
  const u16* __restrict__ Bm = isOut ? Bq : (z == 0 ? Bq : (z == 1 ? Bk : Bv));
  const int wm = (w & 1) * 64, wn = (w >> 1) * 64;

  f32x4 acc[4][4];
#pragma unroll
  for (int i = 0; i < 4; i++)
#pragma unroll
    for (int j = 0; j < 4; j++) acc[i][j] = (f32x4){0.f, 0.f, 0.f, 0.f};

  for (int k0 = 0; k0 < 2048; k0 += 32) {
    __syncthreads();
#pragma unroll
    for (int p = 0; p < 2; p++) {
      int idx = p * 256 + tid;
      int row = idx >> 2;
      int col = (idx & 3) * 8;
      *(uint4*)&As[row * LDA + col] = *(const uint4*)&A[(size_t)(m0 + row) * 2048 + k0 + col];
      *(uint4*)&Bs[row * LDA + col] = *(const uint4*)&Bm[(size_t)(n0 + row) * 2048 + k0 + col];
    }
    __syncthreads();
    short8 af[4], bf[4];
#pragma unroll
    for (int i = 0; i < 4; i++) af[i] = *(const short8*)&As[(wm + i * 16 + lm) * LDA + quad * 8];
#pragma unroll
    for (int j = 0; j < 4; j++) bf[j] = *(const short8*)&Bs[(wn + j * 16 + lm) * LDA + quad * 8];
#pragma unroll
    for (int i = 0; i < 4; i++)
#pragma unroll
      for (int j = 0; j < 4; j++)
        acc[i][j] = __builtin_amdgcn_mfma_f32_16x16x32_bf16(af[i], bf[j], acc[i][j], 0, 0, 0);
  }

  if (isOut) {
#pragma unroll
    for (int i = 0; i < 4; i++)
#pragma unroll
      for (int j = 0; j < 4; j++) {
        int mrow = m0 + wm + i * 16 + quad * 4;
        int ncol = n0 + wn + j * 16 + lm;
#pragma unroll
        for (int r = 0; r < 4; r++)
          Cout[(size_t)(mrow + r) * 2048 + ncol] = acc[i][j][r];
      }
  } else {
#pragma unroll
    for (int i = 0; i < 4; i++)
#pragma unroll
      for (int j = 0; j < 4; j++) {
        int mbase = m0 + wm + i * 16 + quad * 4;
        int n = n0 + wn + j * 16 + lm;
        int b = mbase >> 11;
        int s = mbase & 2047;
        int h = n >> 7, hd = n & 127;
        if (z == 0) {
#pragma unroll
          for (int r = 0; r < 4; r++)
            Qb[((size_t)(b * 16 + h) * 2048 + s + r) * 128 + hd] = f2b(acc[i][j][r]);
        } else if (z == 1) {
#pragma unroll
          for (int r = 0; r < 4; r++)
            Kb[((size_t)(b * 16 + h) * 4096 + 2048 + s + r) * 128 + hd] = f2b(acc[i][j][r]);
        } else {
          u64 pv = (u64)f2b(acc[i][j][0]) |
                   ((u64)f2b(acc[i][j][1]) << 16) |
                   ((u64)f2b(acc[i][j][2]) << 32) |
                   ((u64)f2b(acc[i][j][3]) << 48);
          *(u64*)&Vt[((size_t)(b * 16 + h) * 128 + hd) * 4096 + 2048 + s] = pv;
        }
      }
  }
}

// ------------------------------------------------------------ attention ----
// Qb [B,H,2048,128], Kb [B,H,4096,128], Vt [B,H,128,4096] (all bf16)
// Per wg: 64 Q rows, 4 waves x 16 rows; 64-key tiles staged via global_load_lds.
// Computes S^T = K.Q^T so C-layout gives 4 consecutive keys/lane (b64 P writes,
// 2-shuffle reductions). LDS chunk-rotation swizzle: pos=(chunk+row)&mask.
#define PSTR 72
__global__ __launch_bounds__(256) void attn_kernel(
    const u16* __restrict__ Qb, const u16* __restrict__ Kb,
    const u16* __restrict__ Vt, u16* __restrict__ attnb) {
  __shared__ u16 Ks[64 * 128];      // 16 KB, rows=key (256B, 16 chunks, swizzled)
  __shared__ u16 Vs[128 * 64];      // 16 KB, rows=hd  (128B,  8 chunks, swizzled)
  __shared__ u16 Plds[4 * 16 * PSTR];  // 9 KB, per-wave P
  const int tid = threadIdx.x;
  const int lane = tid & 63, w = tid >> 6;
  const int quad = lane >> 4, lm = lane & 15;
  const int s0 = blockIdx.x * 64;
  const int bh = blockIdx.y;
  const int b = bh >> 4, h = bh & 15;
  const u16* __restrict__ Qp = Qb + (size_t)bh * 2048 * 128;
  const u16* __restrict__ Kp = Kb + (size_t)bh * 4096 * 128;
  const u16* __restrict__ Vp = Vt + (size_t)bh * 128 * 4096;
  const int srow = s0 + w * 16;
  u16* __restrict__ myP = &Plds[w * 16 * PSTR];

  // Q fragments (B-operand of S^T = K.Q^T): B[n=qrow][k=hd]
  short8 qf[4];
#pragma unroll
  for (int c = 0; c < 4; c++)
    qf[c] = *(const short8*)&Qp[(size_t)(srow + lm) * 128 + c * 32 + quad * 8];

  // per-lane staging offsets (chunk rotation: stored pos p holds chunk (p-row)&mask)
  int koff[4], voff[4];
#pragma unroll
  for (int ii = 0; ii < 4; ii++) {
    int row = 16 * w + 4 * ii + (lane >> 4);       // key row in tile
    int ch = ((lane & 15) - row) & 15;
    koff[ii] = row * 128 + ch * 8;
  }
#pragma unroll
  for (int jj = 0; jj < 4; jj++) {
    int row = 32 * w + 8 * jj + (lane >> 3);       // hd row
    int ch = ((lane & 7) - row) & 7;
    voff[jj] = row * 4096 + ch * 8;
  }

  float m_i = NEG_BIG, l_i = 0.f;
  f32x4 oacc[8];
#pragma unroll
  for (int n = 0; n < 8; n++) oacc[n] = (f32x4){0.f, 0.f, 0.f, 0.f};

  const float scale = 0.08838834764831845f;  // 1/sqrt(128)
  const int qabs = 2048 + srow + lm;         // absolute pos of this lane's query row
  const int ntiles = 33 + blockIdx.x;        // (2048 + s0 + 64) / 64

  for (int tile = 0; tile < ntiles; tile++) {
    const int j0 = tile * 64;
    __syncthreads();                         // WAR: prev tile's Ks/Vs reads done
    const u16* kg = Kp + (size_t)j0 * 128;
    const u16* vg = Vp + j0;
#pragma unroll
    for (int ii = 0; ii < 4; ii++) gl_lds16(kg + koff[ii], &Ks[(w * 4 + ii) * 512]);
#pragma unroll
    for (int jj = 0; jj < 4; jj++) gl_lds16(vg + voff[jj], &Vs[(w * 4 + jj) * 512]);
    __syncthreads();                         // drains vmcnt: staging visible

    // ---- S^T = K.Q^T : lane holds keys quad*4+r, qrow lm ----
    f32x4 sacc[4];
#pragma unroll
    for (int t = 0; t < 4; t++) sacc[t] = (f32x4){0.f, 0.f, 0.f, 0.f};
#pragma unroll
    for (int c = 0; c < 4; c++)
#pragma unroll
      for (int t = 0; t < 4; t++) {
        int row = t * 16 + lm;
        int pos = (c * 4 + quad + row) & 15;
        short8 kf = *(const short8*)&Ks[row * 128 + pos * 8];
        sacc[t] = __builtin_amdgcn_mfma_f32_16x16x32_bf16(kf, qf[c], sacc[t], 0, 0, 0);
      }

    // ---- scale + causal mask + row max (row fixed per lane = lm) ----
    float tm = NEG_BIG;
#pragma unroll
    for (int t = 0; t < 4; t++)
#pragma unroll
      for (int r = 0; r < 4; r++) {
        float sv = sacc[t][r] * scale;
        int key = j0 + t * 16 + quad * 4 + r;
        sv = (key > qabs) ? NEG_BIG : sv;
        sacc[t][r] = sv;
        tm = fmaxf(tm, sv);
      }
    tm = fmaxf(tm, __shfl_xor(tm, 16, 64));
    tm = fmaxf(tm, __shfl_xor(tm, 32, 64));
    float mn = fmaxf(m_i, tm);
    float alpha = __expf(m_i - mn);
    m_i = mn;
    float ts = 0.f;
#pragma unroll
    for (int t = 0; t < 4; t++) {
      u64 pv = 0;
#pragma unroll
      for (int r = 0; r < 4; r++) {
        float p = __expf(sacc[t][r] - mn);
        ts += p;
        pv |= (u64)f2b(p) << (16 * r);
      }
      *(u64*)&myP[lm * PSTR + t * 16 + quad * 4] = pv;   // P[qrow=lm][key]
    }
    ts += __shfl_xor(ts, 16, 64);
    ts += __shfl_xor(ts, 32, 64);
    l_i = l_i * alpha + ts;
    // redistribute alpha (indexed by qrow=lm) to C-layout rows quad*4+r
    float ar[4];
#pragma unroll
    for (int r = 0; r < 4; r++) ar[r] = __shfl(alpha, quad * 4 + r, 64);
#pragma unroll
    for (int n = 0; n < 8; n++)
#pragma unroll
      for (int r = 0; r < 4; r++) oacc[n][r] *= ar[r];

    __builtin_amdgcn_fence(__ATOMIC_ACQ_REL, "workgroup");  // P visible (wave-private)

    // ---- O += P.V : A = P (from LDS), B = Vs rows (hd-major) ----
    short8 pf[2];
#pragma unroll
    for (int c = 0; c < 2; c++)
      pf[c] = *(const short8*)&myP[lm * PSTR + c * 32 + quad * 8];
#pragma unroll
    for (int c = 0; c < 2; c++)
#pragma unroll
      for (int n = 0; n < 8; n++) {
        int row = n * 16 + lm;
        int pos = (c * 4 + quad + row) & 7;
        short8 vf = *(const short8*)&Vs[row * 64 + pos * 8];
        oacc[n] = __builtin_amdgcn_mfma_f32_16x16x32_bf16(pf[c], vf, oacc[n], 0, 0, 0);
      }
  }

  // ---- epilogue ----
  float linv = 1.0f / l_i;
  float lr[4];
#pragma unroll
  for (int r = 0; r < 4; r++) lr[r] = __shfl(linv, quad * 4 + r, 64);
#pragma unroll
  for (int r = 0; r < 4; r++) {
    int row = srow + quad * 4 + r;
#pragma unroll
    for (int n = 0; n < 8; n++)
      attnb[((size_t)b * 2048 + row) * 2048 + h * 128 + n * 16 + lm] = f2b(oacc[n][r] * lr[r]);
  }
}

// ---------------------------------------------------------------- launch ---
extern "C" void kernel_launch(void* const* d_in, const int* in_sizes, int n_in,
                              void* d_out, int out_size, void* d_ws, size_t ws_size,
                              hipStream_t stream) {
  const float* hs = (const float*)d_in[0];
  const float* Wq = (const float*)d_in[1];
  const float* Wk = (const float*)d_in[2];
  const float* Wv = (const float*)d_in[3];
  const float* Wo = (const float*)d_in[4];
  const float* kc = (const float*)d_in[5];
  const float* vc = (const float*)d_in[6];
  float* out = (float*)d_out;
  if (ws_size < (size_t)134217728) return;  // need 128 MiB

  char* ws = (char*)d_ws;
  u16* Xb  = (u16*)(ws);                 // 16 MiB (reused as attnb)
  u16* Wqb = (u16*)(ws + 16777216);
  u16* Wkb = Wqb + 4194304;
  u16* Wvb = Wqb + 8388608;
  u16* Wob = Wqb + 12582912;
  u16* Kb  = (u16*)(ws + 50331648);      // [B,H,4096,128]
  u16* Vt  = (u16*)(ws + 83886080);      // [B,H,128,4096]
  u16* Qb  = (u16*)(ws + 117440512);     // [B,H,2048,128]
  u16* attnb = Xb;

  cast_f32_bf16<<<8192, 256, 0, stream>>>(hs, Xb, 2097152);
  cast_f32_bf16<<<4096, 256, 0, stream>>>(Wq, Wqb, 1048576);
  cast_f32_bf16<<<4096, 256, 0, stream>>>(Wk, Wkb, 1048576);
  cast_f32_bf16<<<4096, 256, 0, stream>>>(Wv, Wvb, 1048576);
  cast_f32_bf16<<<4096, 256, 0, stream>>>(Wo, Wob, 1048576);
  cast_kcache<<<8192, 256, 0, stream>>>(kc, Kb);
  transpose_v<<<dim3(32, 32), 256, 0, stream>>>(vc, Vt);
  gemm_bt<<<dim3(16, 32, 3), 256, 0, stream>>>(Xb, Wqb, Wkb, Wvb, Qb, Kb, Vt, nullptr, 0);
  attn_kernel<<<dim3(32, 32), 256, 0, stream>>>(Qb, Kb, Vt, attnb);
  gemm_bt<<<dim3(16, 32, 1), 256, 0, stream>>>(attnb, Wob, nullptr, nullptr,
                                               nullptr, nullptr, nullptr, out, 1);
}

// Round 3
// 602.744 us; speedup vs baseline: 2.4102x; 1.1925x over previous
//
#include <hip/hip_runtime.h>
#include <hip/hip_bf16.h>

typedef __attribute__((ext_vector_type(8))) short short8;
typedef __attribute__((ext_vector_type(4))) float f32x4;
typedef unsigned short u16;
typedef unsigned long long u64;

#define NEG_BIG (-1e30f)

#if __has_builtin(__builtin_amdgcn_exp2f)
#define EXP2(x) __builtin_amdgcn_exp2f(x)
#else
#define EXP2(x) exp2f(x)
#endif

__device__ __forceinline__ u16 f2b(float x) {
  unsigned u = __float_as_uint(x);
  u += 0x7FFFu + ((u >> 16) & 1u);   // round-to-nearest-even bf16
  return (u16)(u >> 16);
}

__device__ __forceinline__ unsigned pkbf(float a, float b) {
  union { __hip_bfloat162 h; unsigned u; } cv;
  cv.h = __float22bfloat162_rn(make_float2(a, b));
  return cv.u;
}

__device__ __forceinline__ void gl_lds16(const u16* g, u16* l) {
  __builtin_amdgcn_global_load_lds(
      (const __attribute__((address_space(1))) unsigned int*)(const void*)g,
      (__attribute__((address_space(3))) unsigned int*)(void*)l, 16, 0, 0);
}

// ---------------------------------------------------------------- casts ----
__global__ __launch_bounds__(256) void cast_f32_bf16(const float* __restrict__ src,
                                                     u16* __restrict__ dst, int n4) {
  int i = blockIdx.x * 256 + threadIdx.x;
  if (i >= n4) return;
  float4 v = ((const float4*)src)[i];
  uint2 pv;
  pv.x = (unsigned)f2b(v.x) | ((unsigned)f2b(v.y) << 16);
  pv.y = (unsigned)f2b(v.z) | ((unsigned)f2b(v.w) << 16);
  ((uint2*)dst)[i] = pv;
}

// k_cache [B,H,2048,128] f32 -> Kb [B,H,4096,128] bf16 (t in [0,2048))
__global__ __launch_bounds__(256) void cast_kcache(const float* __restrict__ src,
                                                   u16* __restrict__ dst) {
  int i = blockIdx.x * 256 + threadIdx.x;
  if (i >= 2097152) return;
  int bh  = i >> 16;
  int rem = i & 65535;
  float4 v = ((const float4*)src)[i];
  uint2 pv;
  pv.x = (unsigned)f2b(v.x) | ((unsigned)f2b(v.y) << 16);
  pv.y = (unsigned)f2b(v.z) | ((unsigned)f2b(v.w) << 16);
  ((uint2*)dst)[(size_t)bh * 131072 + rem] = pv;
}

// v_cache [B,H,2048,128] f32 -> Vt [B,H,128,4096] bf16 (t in [0,2048))
__global__ __launch_bounds__(256) void transpose_v(const float* __restrict__ src,
                                                   u16* __restrict__ dst) {
  __shared__ u16 lds[128 * 68];
  const int tid = threadIdx.x;
  const int bh = blockIdx.y;
  const int t0 = blockIdx.x * 64;
#pragma unroll
  for (int p = 0; p < 8; p++) {
    int idx = p * 256 + tid;
    int t = idx >> 5;
    int d4 = (idx & 31) * 4;
    float4 v = *(const float4*)&src[(((size_t)bh * 2048) + t0 + t) * 128 + d4];
    lds[(d4 + 0) * 68 + t] = f2b(v.x);
    lds[(d4 + 1) * 68 + t] = f2b(v.y);
    lds[(d4 + 2) * 68 + t] = f2b(v.z);
    lds[(d4 + 3) * 68 + t] = f2b(v.w);
  }
  __syncthreads();
  const int d = tid >> 1;
  const int th = (tid & 1) * 32;
  size_t obase = ((size_t)bh * 128 + d) * 4096 + t0 + th;
#pragma unroll
  for (int jb = 0; jb < 4; jb++) {
    const u16* lp = &lds[d * 68 + th + jb * 8];
    uint4 pv;
    pv.x = (unsigned)lp[0] | ((unsigned)lp[1] << 16);
    pv.y = (unsigned)lp[2] | ((unsigned)lp[3] << 16);
    pv.z = (unsigned)lp[4] | ((unsigned)lp[5] << 16);
    pv.w = (unsigned)lp[6] | ((unsigned)lp[7] << 16);
    *(uint4*)&dst[obase + jb * 8] = pv;
  }
}

// ---------------------------------------------------------------- GEMM -----
// m97 recipe: BK=64, global_load_lds width=16, rotation-swizzled unpadded LDS.
// C[m,n] = sum_k A[m*2048+k]*Bm[n*2048+k]; z scatter (Q prescaled) or fp32 out.
#define QS (0.08838834764831845f * 1.4426950408889634f)  // 1/sqrt(128)*log2(e)
__global__ __launch_bounds__(256) void gemm_bt(
    const u16* __restrict__ A, const u16* __restrict__ Bq,
    const u16* __restrict__ Bk, const u16* __restrict__ Bv,
    u16* __restrict__ Qb, u16* __restrict__ Kb, u16* __restrict__ Vt,
    float* __restrict__ Cout, int isOut) {
  __shared__ u16 As[128 * 64];   // 16 KB, row=m, 128B/row, 8 chunks rotated
  __shared__ u16 Bs[128 * 64];
  const int tid = threadIdx.x;
  const int lane = tid & 63, w = tid >> 6;
  const int quad = lane >> 4, lm = lane & 15;
  const int n0 = blockIdx.x * 128, m0 = blockIdx.y * 128;
  const int z = blockIdx.z;
  const u16* __restrict__ Bm = isOut ? Bq : (z == 0 ? Bq : (z == 1 ? Bk : Bv));
  const int wm = (w & 1) * 64, wn = (w >> 1) * 64;

  int grow[4], gch[4];
#pragma unroll
  for (int ii = 0; ii < 4; ii++) {
    int r = w * 32 + ii * 8 + (lane >> 3);
    grow[ii] = r;
    gch[ii] = ((lane & 7) - r) & 7;
  }

  f32x4 acc[4][4];
#pragma unroll
  for (int i = 0; i < 4; i++)
#pragma unroll
    for (int j = 0; j < 4; j++) acc[i][j] = (f32x4){0.f, 0.f, 0.f, 0.f};

  for (int k0 = 0; k0 < 2048; k0 += 64) {
    __syncthreads();
#pragma unroll
    for (int ii = 0; ii < 4; ii++)
      gl_lds16(A + (size_t)(m0 + grow[ii]) * 2048 + k0 + gch[ii] * 8,
               &As[(w * 32 + ii * 8) * 64]);
#pragma unroll
    for (int ii = 0; ii < 4; ii++)
      gl_lds16(Bm + (size_t)(n0 + grow[ii]) * 2048 + k0 + gch[ii] * 8,
               &Bs[(w * 32 + ii * 8) * 64]);
    __syncthreads();
    short8 af[2][4], bf[2][4];
#pragma unroll
    for (int c = 0; c < 2; c++)
#pragma unroll
      for (int i = 0; i < 4; i++) {
        int row = wm + i * 16 + lm;
        af[c][i] = *(const short8*)&As[row * 64 + ((c * 4 + quad + row) & 7) * 8];
      }
#pragma unroll
    for (int c = 0; c < 2; c++)
#pragma unroll
      for (int j = 0; j < 4; j++) {
        int row = wn + j * 16 + lm;
        bf[c][j] = *(const short8*)&Bs[row * 64 + ((c * 4 + quad + row) & 7) * 8];
      }
#pragma unroll
    for (int c = 0; c < 2; c++)
#pragma unroll
      for (int i = 0; i < 4; i++)
#pragma unroll
        for (int j = 0; j < 4; j++)
          acc[i][j] = __builtin_amdgcn_mfma_f32_16x16x32_bf16(af[c][i], bf[c][j], acc[i][j], 0, 0, 0);
  }

  if (isOut) {
#pragma unroll
    for (int i = 0; i < 4; i++)
#pragma unroll
      for (int j = 0; j < 4; j++) {
        int mrow = m0 + wm + i * 16 + quad * 4;
        int ncol = n0 + wn + j * 16 + lm;
#pragma unroll
        for (int r = 0; r < 4; r++)
          Cout[(size_t)(mrow + r) * 2048 + ncol] = acc[i][j][r];
      }
  } else {
#pragma unroll
    for (int i = 0; i < 4; i++)
#pragma unroll
      for (int j = 0; j < 4; j++) {
        int mbase = m0 + wm + i * 16 + quad * 4;
        int n = n0 + wn + j * 16 + lm;
        int b = mbase >> 11;
        int s = mbase & 2047;
        int h = n >> 7, hd = n & 127;
        if (z == 0) {
#pragma unroll
          for (int r = 0; r < 4; r++)
            Qb[((size_t)(b * 16 + h) * 2048 + s + r) * 128 + hd] = f2b(acc[i][j][r] * QS);
        } else if (z == 1) {
#pragma unroll
          for (int r = 0; r < 4; r++)
            Kb[((size_t)(b * 16 + h) * 4096 + 2048 + s + r) * 128 + hd] = f2b(acc[i][j][r]);
        } else {
          u64 pv = (u64)f2b(acc[i][j][0]) |
                   ((u64)f2b(acc[i][j][1]) << 16) |
                   ((u64)f2b(acc[i][j][2]) << 32) |
                   ((u64)f2b(acc[i][j][3]) << 48);
          *(u64*)&Vt[((size_t)(b * 16 + h) * 128 + hd) * 4096 + 2048 + s] = pv;
        }
      }
  }
}

// ------------------------------------------------------------ attention ----
// 4 waves x 32 qrows = 128 qrows/wg; paired q-blocks (qb, 15-qb) -> 256 wgs.
// Ks double-buffered; Vs staged at tile top (drained at mid barrier).
// S^T = K.Q^T (C-layout: col=qrow, row=key); P per-wave in rotated LDS.
__global__ __launch_bounds__(256, 2) void attn_kernel(
    const u16* __restrict__ Qb, const u16* __restrict__ Kb,
    const u16* __restrict__ Vt, u16* __restrict__ attnb) {
  __shared__ u16 Ks[2][64 * 128];   // 2x16KB, row=key, 256B/row, 16 chunks rot.
  __shared__ u16 Vs[128 * 64];      // 16KB, row=hd, 128B/row, 8 chunks rot.
  __shared__ u16 Pl[4 * 32 * 64];   // 16KB, per-wave 32x64, 8 chunks rot.
  const int tid = threadIdx.x;
  const int lane = tid & 63, w = tid >> 6;
  const int quad = lane >> 4, lm = lane & 15;
  const int bh = blockIdx.x;
  const int b = bh >> 4, h = bh & 15;
  const u16* __restrict__ Qp = Qb + (size_t)bh * 2048 * 128;
  const u16* __restrict__ Kp = Kb + (size_t)bh * 4096 * 128;
  const u16* __restrict__ Vp = Vt + (size_t)bh * 128 * 4096;
  u16* __restrict__ myP = &Pl[w * 2048];

  // staging offsets (chunk rotation by tile-local row)
  int koff[4], voff[4];
#pragma unroll
  for (int ii = 0; ii < 4; ii++) {
    int row = 16 * w + 4 * ii + (lane >> 4);
    koff[ii] = row * 128 + (((lane & 15) - row) & 15) * 8;
  }
#pragma unroll
  for (int jj = 0; jj < 4; jj++) {
    int row = 32 * w + 8 * jj + (lane >> 3);
    voff[jj] = row * 4096 + (((lane & 7) - row) & 7) * 8;
  }

  for (int qq = 0; qq < 2; qq++) {
    const int qb = qq ? (15 - (int)blockIdx.y) : (int)blockIdx.y;
    const int s0 = qb * 128;
    const int ntiles = 34 + 2 * qb;       // (2048 + s0 + 128)/64
    const int qa_min = 2048 + s0 + w * 32;

    short8 qf[2][4];
#pragma unroll
    for (int u = 0; u < 2; u++)
#pragma unroll
      for (int c = 0; c < 4; c++)
        qf[u][c] = *(const short8*)&Qp[(size_t)(s0 + w * 32 + u * 16 + lm) * 128 + c * 32 + quad * 8];

    float m_i[2] = {NEG_BIG, NEG_BIG}, l_i[2] = {0.f, 0.f};
    f32x4 oacc[2][8];
#pragma unroll
    for (int u = 0; u < 2; u++)
#pragma unroll
      for (int n = 0; n < 8; n++) oacc[u][n] = (f32x4){0.f, 0.f, 0.f, 0.f};

    // prologue: stage K tile 0 into buf 0
#pragma unroll
    for (int ii = 0; ii < 4; ii++) gl_lds16(Kp + koff[ii], &Ks[0][(w * 4 + ii) * 512]);
    __syncthreads();

    for (int t = 0; t < ntiles; t++) {
      const int cur = t & 1;
      const int j0 = t * 64;
      // stage next K tile + this tile's V (drain at mid barrier)
      if (t + 1 < ntiles) {
        const u16* kg = Kp + (size_t)(j0 + 64) * 128;
#pragma unroll
        for (int ii = 0; ii < 4; ii++) gl_lds16(kg + koff[ii], &Ks[cur ^ 1][(w * 4 + ii) * 512]);
      }
      {
        const u16* vg = Vp + j0;
#pragma unroll
        for (int jj = 0; jj < 4; jj++) gl_lds16(vg + voff[jj], &Vs[(w * 4 + jj) * 512]);
      }

      // ---- S^T = K.Q^T from Ks[cur] ----
      f32x4 sacc[4][2];
#pragma unroll
      for (int kt = 0; kt < 4; kt++)
#pragma unroll
        for (int u = 0; u < 2; u++) sacc[kt][u] = (f32x4){0.f, 0.f, 0.f, 0.f};
#pragma unroll
      for (int c = 0; c < 4; c++)
#pragma unroll
        for (int kt = 0; kt < 4; kt++) {
          int row = kt * 16 + lm;
          short8 kf = *(const short8*)&Ks[cur][row * 128 + ((c * 4 + quad + row) & 15) * 8];
          sacc[kt][0] = __builtin_amdgcn_mfma_f32_16x16x32_bf16(kf, qf[0][c], sacc[kt][0], 0, 0, 0);
          sacc[kt][1] = __builtin_amdgcn_mfma_f32_16x16x32_bf16(kf, qf[1][c], sacc[kt][1], 0, 0, 0);
        }

      // ---- mask (only when wave-uniformly needed) ----
      if (j0 + 63 > qa_min) {
#pragma unroll
        for (int u = 0; u < 2; u++) {
          int qabs = qa_min + u * 16 + lm;
#pragma unroll
          for (int kt = 0; kt < 4; kt++)
#pragma unroll
            for (int r = 0; r < 4; r++) {
              int key = j0 + kt * 16 + quad * 4 + r;
              if (key > qabs) sacc[kt][u][r] = NEG_BIG;
            }
        }
      }

      // ---- online softmax (exp2 domain; Q prescaled by scale*log2e) ----
      float al[2];
#pragma unroll
      for (int u = 0; u < 2; u++) {
        float tm = NEG_BIG;
#pragma unroll
        for (int kt = 0; kt < 4; kt++)
#pragma unroll
          for (int r = 0; r < 4; r++) tm = fmaxf(tm, sacc[kt][u][r]);
        tm = fmaxf(tm, __shfl_xor(tm, 16, 64));
        tm = fmaxf(tm, __shfl_xor(tm, 32, 64));
        float mn = fmaxf(m_i[u], tm);
        al[u] = EXP2(m_i[u] - mn);
        m_i[u] = mn;
        float ts = 0.f;
#pragma unroll
        for (int kt = 0; kt < 4; kt++) {
          float p0 = EXP2(sacc[kt][u][0] - mn);
          float p1 = EXP2(sacc[kt][u][1] - mn);
          float p2 = EXP2(sacc[kt][u][2] - mn);
          float p3 = EXP2(sacc[kt][u][3] - mn);
          ts += (p0 + p1) + (p2 + p3);
          u64 pv = (u64)pkbf(p0, p1) | ((u64)pkbf(p2, p3) << 32);
          int row = u * 16 + lm;
          int pos = ((2 * kt + (quad >> 1)) + row) & 7;
          *(u64*)&myP[row * 64 + pos * 8 + (quad & 1) * 4] = pv;
        }
        ts += __shfl_xor(ts, 16, 64);
        ts += __shfl_xor(ts, 32, 64);
        l_i[u] = l_i[u] * al[u] + ts;
      }
      // rescale O (skipped when both alphas == 1)
      if (__any(al[0] + al[1] < 2.0f)) {
        float ar[2][4];
#pragma unroll
        for (int u = 0; u < 2; u++)
#pragma unroll
          for (int r = 0; r < 4; r++) ar[u][r] = __shfl(al[u], quad * 4 + r, 64);
#pragma unroll
        for (int u = 0; u < 2; u++)
#pragma unroll
          for (int n = 0; n < 8; n++)
#pragma unroll
            for (int r = 0; r < 4; r++) oacc[u][n][r] *= ar[u][r];
      }
      __builtin_amdgcn_fence(__ATOMIC_ACQ_REL, "workgroup");
      __syncthreads();   // drains Vs(t) [+ Ks(t+1)]; P visible

      // ---- O += P.V from Vs ----
#pragma unroll
      for (int c = 0; c < 2; c++) {
        short8 pf[2];
#pragma unroll
        for (int u = 0; u < 2; u++) {
          int row = u * 16 + lm;
          pf[u] = *(const short8*)&myP[row * 64 + ((c * 4 + quad + row) & 7) * 8];
        }
#pragma unroll
        for (int n = 0; n < 8; n++) {
          int row = n * 16 + lm;
          short8 vf = *(const short8*)&Vs[row * 64 + ((c * 4 + quad + row) & 7) * 8];
          oacc[0][n] = __builtin_amdgcn_mfma_f32_16x16x32_bf16(pf[0], vf, oacc[0][n], 0, 0, 0);
          oacc[1][n] = __builtin_amdgcn_mfma_f32_16x16x32_bf16(pf[1], vf, oacc[1][n], 0, 0, 0);
        }
      }
      __syncthreads();   // WAR: Vs/P/Ks[cur^1] reads done before next stage
    }

    // ---- epilogue ----
#pragma unroll
    for (int u = 0; u < 2; u++) {
      float linv = 1.0f / l_i[u];
      float lr[4];
#pragma unroll
      for (int r = 0; r < 4; r++) lr[r] = __shfl(linv, quad * 4 + r, 64);
#pragma unroll
      for (int r = 0; r < 4; r++) {
        int row = s0 + w * 32 + u * 16 + quad * 4 + r;
#pragma unroll
        for (int n = 0; n < 8; n++)
          attnb[((size_t)b * 2048 + row) * 2048 + h * 128 + n * 16 + lm] = f2b(oacc[u][n][r] * lr[r]);
      }
    }
    __syncthreads();   // protect Ks buf 0 before next q-block's prologue stage
  }
}

// ---------------------------------------------------------------- launch ---
extern "C" void kernel_launch(void* const* d_in, const int* in_sizes, int n_in,
                              void* d_out, int out_size, void* d_ws, size_t ws_size,
                              hipStream_t stream) {
  const float* hs = (const float*)d_in[0];
  const float* Wq = (const float*)d_in[1];
  const float* Wk = (const float*)d_in[2];
  const float* Wv = (const float*)d_in[3];
  const float* Wo = (const float*)d_in[4];
  const float* kc = (const float*)d_in[5];
  const float* vc = (const float*)d_in[6];
  float* out = (float*)d_out;
  if (ws_size < (size_t)134217728) return;  // need 128 MiB

  char* ws = (char*)d_ws;
  u16* Xb  = (u16*)(ws);                 // 16 MiB (reused as attnb)
  u16* Wqb = (u16*)(ws + 16777216);
  u16* Wkb = Wqb + 4194304;
  u16* Wvb = Wqb + 8388608;
  u16* Wob = Wqb + 12582912;
  u16* Kb  = (u16*)(ws + 50331648);      // [B,H,4096,128]
  u16* Vt  = (u16*)(ws + 83886080);      // [B,H,128,4096]
  u16* Qb  = (u16*)(ws + 117440512);     // [B,H,2048,128]
  u16* attnb = Xb;

  cast_f32_bf16<<<8192, 256, 0, stream>>>(hs, Xb, 2097152);
  cast_f32_bf16<<<4096, 256, 0, stream>>>(Wq, Wqb, 1048576);
  cast_f32_bf16<<<4096, 256, 0, stream>>>(Wk, Wkb, 1048576);
  cast_f32_bf16<<<4096, 256, 0, stream>>>(Wv, Wvb, 1048576);
  cast_f32_bf16<<<4096, 256, 0, stream>>>(Wo, Wob, 1048576);
  cast_kcache<<<8192, 256, 0, stream>>>(kc, Kb);
  transpose_v<<<dim3(32, 32), 256, 0, stream>>>(vc, Vt);
  gemm_bt<<<dim3(16, 32, 3), 256, 0, stream>>>(Xb, Wqb, Wkb, Wvb, Qb, Kb, Vt, nullptr, 0);
  attn_kernel<<<dim3(32, 8), 256, 0, stream>>>(Qb, Kb, Vt, attnb);
  gemm_bt<<<dim3(16, 32, 1), 256, 0, stream>>>(attnb, Wob, nullptr, nullptr,
                                               nullptr, nullptr, nullptr, out, 1);
}

// Round 5
// 534.925 us; speedup vs baseline: 2.7157x; 1.1268x over previous
//
#include <hip/hip_runtime.h>
#include <hip/hip_bf16.h>

typedef __attribute__((ext_vector_type(8))) short short8;
typedef __attribute__((ext_vector_type(4))) float f32x4;
typedef unsigned short u16;
typedef unsigned long long u64;

#define NEG_BIG (-1e30f)

#if __has_builtin(__builtin_amdgcn_exp2f)
#define EXP2(x) __builtin_amdgcn_exp2f(x)
#else
#define EXP2(x) exp2f(x)
#endif

__device__ __forceinline__ u16 f2b(float x) {
  unsigned u = __float_as_uint(x);
  u += 0x7FFFu + ((u >> 16) & 1u);   // round-to-nearest-even bf16
  return (u16)(u >> 16);
}

__device__ __forceinline__ unsigned pkbf(float a, float b) {
  union { __hip_bfloat162 h; unsigned u; } cv;
  cv.h = __float22bfloat162_rn(make_float2(a, b));
  return cv.u;
}

__device__ __forceinline__ void gl_lds16(const u16* g, u16* l) {
  __builtin_amdgcn_global_load_lds(
      (const __attribute__((address_space(1))) unsigned int*)(const void*)g,
      (__attribute__((address_space(3))) unsigned int*)(void*)l, 16, 0, 0);
}

// ---------------------------------------------------------------- casts ----
// y=0,1: hs halves -> Xb; y=2..5: Wq/Wk/Wv/Wo -> Wqb stack; y=6,7: kcache -> Kb.
// Explicit indexing per branch (R4's folded pointer arith dropped the i term).
__global__ __launch_bounds__(256) void cast_all(
    const float* __restrict__ hs, const float* __restrict__ Wq,
    const float* __restrict__ Wk, const float* __restrict__ Wv,
    const float* __restrict__ Wo, const float* __restrict__ kc,
    u16* __restrict__ Xb, u16* __restrict__ Wqb, u16* __restrict__ Kb) {
  const int y = blockIdx.y;
  const size_t i = (size_t)blockIdx.x * 256 + threadIdx.x;   // float4 idx in segment
  const float4* src4;
  uint2* dst;
  size_t didx;
  if (y < 2) {
    src4 = (const float4*)hs + (size_t)y * 1048576 + i;
    dst  = (uint2*)Xb;
    didx = (size_t)y * 1048576 + i;
  } else if (y < 6) {
    const float* wsrc[4] = {Wq, Wk, Wv, Wo};
    src4 = (const float4*)wsrc[y - 2] + i;
    dst  = (uint2*)Wqb;
    didx = (size_t)(y - 2) * 1048576 + i;
  } else {
    size_t g = (size_t)(y - 6) * 1048576 + i;   // global float4 idx into kcache
    src4 = (const float4*)kc + g;
    dst  = (uint2*)Kb;
    didx = (g >> 16) * 131072 + (g & 65535);    // bh stride 131072 uint2, t<2048 half
  }
  float4 v = *src4;
  uint2 pv;
  pv.x = pkbf(v.x, v.y);
  pv.y = pkbf(v.z, v.w);
  dst[didx] = pv;
}

// v_cache [B,H,2048,128] f32 -> Vt [B,H,128,4096] bf16 (t in [0,2048))
__global__ __launch_bounds__(256) void transpose_v(const float* __restrict__ src,
                                                   u16* __restrict__ dst) {
  __shared__ u16 lds[128 * 68];
  const int tid = threadIdx.x;
  const int bh = blockIdx.y;
  const int t0 = blockIdx.x * 64;
#pragma unroll
  for (int p = 0; p < 8; p++) {
    int idx = p * 256 + tid;
    int t = idx >> 5;
    int d4 = (idx & 31) * 4;
    float4 v = *(const float4*)&src[(((size_t)bh * 2048) + t0 + t) * 128 + d4];
    lds[(d4 + 0) * 68 + t] = f2b(v.x);
    lds[(d4 + 1) * 68 + t] = f2b(v.y);
    lds[(d4 + 2) * 68 + t] = f2b(v.z);
    lds[(d4 + 3) * 68 + t] = f2b(v.w);
  }
  __syncthreads();
  const int d = tid >> 1;
  const int th = (tid & 1) * 32;
  size_t obase = ((size_t)bh * 128 + d) * 4096 + t0 + th;
#pragma unroll
  for (int jb = 0; jb < 4; jb++) {
    const u16* lp = &lds[d * 68 + th + jb * 8];
    uint4 pv;
    pv.x = (unsigned)lp[0] | ((unsigned)lp[1] << 16);
    pv.y = (unsigned)lp[2] | ((unsigned)lp[3] << 16);
    pv.z = (unsigned)lp[4] | ((unsigned)lp[5] << 16);
    pv.w = (unsigned)lp[6] | ((unsigned)lp[7] << 16);
    *(uint4*)&dst[obase + jb * 8] = pv;
  }
}

// ---------------------------------------------------------------- GEMM -----
// m97 recipe: BK=64, global_load_lds width=16, rotation-swizzled unpadded LDS.
// isOut=0: B = stacked [Wq;Wk;Wv] (N=6144), scatter by z=n>>11 (Q prescaled).
// isOut=1: B = Wo (N=2048), fp32 row-major out.
#define QS (0.08838834764831845f * 1.4426950408889634f)  // 1/sqrt(128)*log2(e)
__global__ __launch_bounds__(256) void gemm_bt(
    const u16* __restrict__ A, const u16* __restrict__ Bq,
    u16* __restrict__ Qb, u16* __restrict__ Kb, u16* __restrict__ Vt,
    float* __restrict__ Cout, int isOut) {
  __shared__ u16 As[128 * 64];   // 16 KB, row=m, 128B/row, 8 chunks rotated
  __shared__ u16 Bs[128 * 64];
  const int tid = threadIdx.x;
  const int lane = tid & 63, w = tid >> 6;
  const int quad = lane >> 4, lm = lane & 15;
  const int n0 = blockIdx.x * 128, m0 = blockIdx.y * 128;
  const int wm = (w & 1) * 64, wn = (w >> 1) * 64;

  int grow[4], gch[4];
#pragma unroll
  for (int ii = 0; ii < 4; ii++) {
    int r = w * 32 + ii * 8 + (lane >> 3);
    grow[ii] = r;
    gch[ii] = ((lane & 7) - r) & 7;
  }

  f32x4 acc[4][4];
#pragma unroll
  for (int i = 0; i < 4; i++)
#pragma unroll
    for (int j = 0; j < 4; j++) acc[i][j] = (f32x4){0.f, 0.f, 0.f, 0.f};

  for (int k0 = 0; k0 < 2048; k0 += 64) {
    __syncthreads();
#pragma unroll
    for (int ii = 0; ii < 4; ii++)
      gl_lds16(A + (size_t)(m0 + grow[ii]) * 2048 + k0 + gch[ii] * 8,
               &As[(w * 32 + ii * 8) * 64]);
#pragma unroll
    for (int ii = 0; ii < 4; ii++)
      gl_lds16(Bq + (size_t)(n0 + grow[ii]) * 2048 + k0 + gch[ii] * 8,
               &Bs[(w * 32 + ii * 8) * 64]);
    __syncthreads();
    short8 af[2][4], bf[2][4];
#pragma unroll
    for (int c = 0; c < 2; c++)
#pragma unroll
      for (int i = 0; i < 4; i++) {
        int row = wm + i * 16 + lm;
        af[c][i] = *(const short8*)&As[row * 64 + ((c * 4 + quad + row) & 7) * 8];
      }
#pragma unroll
    for (int c = 0; c < 2; c++)
#pragma unroll
      for (int j = 0; j < 4; j++) {
        int row = wn + j * 16 + lm;
        bf[c][j] = *(const short8*)&Bs[row * 64 + ((c * 4 + quad + row) & 7) * 8];
      }
#pragma unroll
    for (int c = 0; c < 2; c++)
#pragma unroll
      for (int i = 0; i < 4; i++)
#pragma unroll
        for (int j = 0; j < 4; j++)
          acc[i][j] = __builtin_amdgcn_mfma_f32_16x16x32_bf16(af[c][i], bf[c][j], acc[i][j], 0, 0, 0);
  }

  if (isOut) {
#pragma unroll
    for (int i = 0; i < 4; i++)
#pragma unroll
      for (int j = 0; j < 4; j++) {
        int mrow = m0 + wm + i * 16 + quad * 4;
        int ncol = n0 + wn + j * 16 + lm;
#pragma unroll
        for (int r = 0; r < 4; r++)
          Cout[(size_t)(mrow + r) * 2048 + ncol] = acc[i][j][r];
      }
  } else {
#pragma unroll
    for (int i = 0; i < 4; i++)
#pragma unroll
      for (int j = 0; j < 4; j++) {
        int mbase = m0 + wm + i * 16 + quad * 4;
        int n = n0 + wn + j * 16 + lm;
        int b = mbase >> 11;
        int s = mbase & 2047;
        int z = n >> 11, nn = n & 2047;
        int h = nn >> 7, hd = nn & 127;
        if (z == 0) {
#pragma unroll
          for (int r = 0; r < 4; r++)
            Qb[((size_t)(b * 16 + h) * 2048 + s + r) * 128 + hd] = f2b(acc[i][j][r] * QS);
        } else if (z == 1) {
#pragma unroll
          for (int r = 0; r < 4; r++)
            Kb[((size_t)(b * 16 + h) * 4096 + 2048 + s + r) * 128 + hd] = f2b(acc[i][j][r]);
        } else {
          u64 pv = (u64)f2b(acc[i][j][0]) |
                   ((u64)f2b(acc[i][j][1]) << 16) |
                   ((u64)f2b(acc[i][j][2]) << 32) |
                   ((u64)f2b(acc[i][j][3]) << 48);
          *(u64*)&Vt[((size_t)(b * 16 + h) * 128 + hd) * 4096 + 2048 + s] = pv;
        }
      }
  }
}

// ------------------------------------------------------------ attention ----
// 4 waves x 32 qrows = 128 qrows/wg; 512 wgs (32 bh x 16 qb).
// y->qb mapped so sequentially-paired wgs (c, c+256) sum to 98 tiles/CU.
// Ks double-buffered; Vs staged at tile top (drained at mid barrier).
// S^T = K.Q^T (C-layout: col=qrow, row=key); P per-wave in rotated LDS.
__global__ __launch_bounds__(256, 2) void attn_kernel(
    const u16* __restrict__ Qb, const u16* __restrict__ Kb,
    const u16* __restrict__ Vt, u16* __restrict__ attnb) {
  __shared__ u16 Ks[2][64 * 128];   // 2x16KB, row=key, 256B/row, 16 chunks rot.
  __shared__ u16 Vs[128 * 64];      // 16KB, row=hd, 128B/row, 8 chunks rot.
  __shared__ u16 Pl[4 * 32 * 64];   // 16KB, per-wave 32x64, 8 chunks rot.
  const int tid = threadIdx.x;
  const int lane = tid & 63, w = tid >> 6;
  const int quad = lane >> 4, lm = lane & 15;
  const int bh = blockIdx.x;
  const int b = bh >> 4, h = bh & 15;
  const int y = blockIdx.y;
  const int qb = (y < 8) ? y : 23 - y;       // pair (y,y+8) -> 98 tiles
  const u16* __restrict__ Qp = Qb + (size_t)bh * 2048 * 128;
  const u16* __restrict__ Kp = Kb + (size_t)bh * 4096 * 128;
  const u16* __restrict__ Vp = Vt + (size_t)bh * 128 * 4096;
  u16* __restrict__ myP = &Pl[w * 2048];

  // staging offsets (chunk rotation by tile-local row)
  int koff[4], voff[4];
#pragma unroll
  for (int ii = 0; ii < 4; ii++) {
    int row = 16 * w + 4 * ii + (lane >> 4);
    koff[ii] = row * 128 + (((lane & 15) - row) & 15) * 8;
  }
#pragma unroll
  for (int jj = 0; jj < 4; jj++) {
    int row = 32 * w + 8 * jj + (lane >> 3);
    voff[jj] = row * 4096 + (((lane & 7) - row) & 7) * 8;
  }

  const int s0 = qb * 128;
  const int ntiles = 34 + 2 * qb;            // (2048 + s0 + 128)/64
  const int qa_min = 2048 + s0 + w * 32;

  short8 qf[2][4];
#pragma unroll
  for (int u = 0; u < 2; u++)
#pragma unroll
    for (int c = 0; c < 4; c++)
      qf[u][c] = *(const short8*)&Qp[(size_t)(s0 + w * 32 + u * 16 + lm) * 128 + c * 32 + quad * 8];

  float m_i[2] = {NEG_BIG, NEG_BIG}, l_i[2] = {0.f, 0.f};
  f32x4 oacc[2][8];
#pragma unroll
  for (int u = 0; u < 2; u++)
#pragma unroll
    for (int n = 0; n < 8; n++) oacc[u][n] = (f32x4){0.f, 0.f, 0.f, 0.f};

  // prologue: stage K tile 0 into buf 0
#pragma unroll
  for (int ii = 0; ii < 4; ii++) gl_lds16(Kp + koff[ii], &Ks[0][(w * 4 + ii) * 512]);
  __syncthreads();

  for (int t = 0; t < ntiles; t++) {
    const int cur = t & 1;
    const int j0 = t * 64;
    // stage next K tile + this tile's V (drain at mid barrier)
    if (t + 1 < ntiles) {
      const u16* kg = Kp + (size_t)(j0 + 64) * 128;
#pragma unroll
      for (int ii = 0; ii < 4; ii++) gl_lds16(kg + koff[ii], &Ks[cur ^ 1][(w * 4 + ii) * 512]);
    }
    {
      const u16* vg = Vp + j0;
#pragma unroll
      for (int jj = 0; jj < 4; jj++) gl_lds16(vg + voff[jj], &Vs[(w * 4 + jj) * 512]);
    }

    // ---- S^T = K.Q^T from Ks[cur] ----
    f32x4 sacc[4][2];
#pragma unroll
    for (int kt = 0; kt < 4; kt++)
#pragma unroll
      for (int u = 0; u < 2; u++) sacc[kt][u] = (f32x4){0.f, 0.f, 0.f, 0.f};
#pragma unroll
    for (int c = 0; c < 4; c++)
#pragma unroll
      for (int kt = 0; kt < 4; kt++) {
        int row = kt * 16 + lm;
        short8 kf = *(const short8*)&Ks[cur][row * 128 + ((c * 4 + quad + row) & 15) * 8];
        sacc[kt][0] = __builtin_amdgcn_mfma_f32_16x16x32_bf16(kf, qf[0][c], sacc[kt][0], 0, 0, 0);
        sacc[kt][1] = __builtin_amdgcn_mfma_f32_16x16x32_bf16(kf, qf[1][c], sacc[kt][1], 0, 0, 0);
      }

    // ---- mask (only when wave-uniformly needed) ----
    if (j0 + 63 > qa_min) {
#pragma unroll
      for (int u = 0; u < 2; u++) {
        int qabs = qa_min + u * 16 + lm;
#pragma unroll
        for (int kt = 0; kt < 4; kt++)
#pragma unroll
          for (int r = 0; r < 4; r++) {
            int key = j0 + kt * 16 + quad * 4 + r;
            if (key > qabs) sacc[kt][u][r] = NEG_BIG;
          }
      }
    }

    // ---- online softmax (exp2 domain; Q prescaled by scale*log2e) ----
    float al[2];
#pragma unroll
    for (int u = 0; u < 2; u++) {
      float tm = NEG_BIG;
#pragma unroll
      for (int kt = 0; kt < 4; kt++)
#pragma unroll
        for (int r = 0; r < 4; r++) tm = fmaxf(tm, sacc[kt][u][r]);
      tm = fmaxf(tm, __shfl_xor(tm, 16, 64));
      tm = fmaxf(tm, __shfl_xor(tm, 32, 64));
      float mn = fmaxf(m_i[u], tm);
      al[u] = EXP2(m_i[u] - mn);
      m_i[u] = mn;
      float ts = 0.f;
#pragma unroll
      for (int kt = 0; kt < 4; kt++) {
        float p0 = EXP2(sacc[kt][u][0] - mn);
        float p1 = EXP2(sacc[kt][u][1] - mn);
        float p2 = EXP2(sacc[kt][u][2] - mn);
        float p3 = EXP2(sacc[kt][u][3] - mn);
        ts += (p0 + p1) + (p2 + p3);
        u64 pv = (u64)pkbf(p0, p1) | ((u64)pkbf(p2, p3) << 32);
        int row = u * 16 + lm;
        int pos = ((2 * kt + (quad >> 1)) + row) & 7;
        *(u64*)&myP[row * 64 + pos * 8 + (quad & 1) * 4] = pv;
      }
      ts += __shfl_xor(ts, 16, 64);
      ts += __shfl_xor(ts, 32, 64);
      l_i[u] = l_i[u] * al[u] + ts;
    }
    // rescale O (skipped when both alphas == 1)
    if (__any(al[0] + al[1] < 2.0f)) {
      float ar[2][4];
#pragma unroll
      for (int u = 0; u < 2; u++)
#pragma unroll
        for (int r = 0; r < 4; r++) ar[u][r] = __shfl(al[u], quad * 4 + r, 64);
#pragma unroll
      for (int u = 0; u < 2; u++)
#pragma unroll
        for (int n = 0; n < 8; n++)
#pragma unroll
          for (int r = 0; r < 4; r++) oacc[u][n][r] *= ar[u][r];
    }
    __builtin_amdgcn_fence(__ATOMIC_ACQ_REL, "workgroup");
    __syncthreads();   // drains Vs(t) [+ Ks(t+1)]; P visible

    // ---- O += P.V from Vs ----
#pragma unroll
    for (int c = 0; c < 2; c++) {
      short8 pf[2];
#pragma unroll
      for (int u = 0; u < 2; u++) {
        int row = u * 16 + lm;
        pf[u] = *(const short8*)&myP[row * 64 + ((c * 4 + quad + row) & 7) * 8];
      }
#pragma unroll
      for (int n = 0; n < 8; n++) {
        int row = n * 16 + lm;
        short8 vf = *(const short8*)&Vs[row * 64 + ((c * 4 + quad + row) & 7) * 8];
        oacc[0][n] = __builtin_amdgcn_mfma_f32_16x16x32_bf16(pf[0], vf, oacc[0][n], 0, 0, 0);
        oacc[1][n] = __builtin_amdgcn_mfma_f32_16x16x32_bf16(pf[1], vf, oacc[1][n], 0, 0, 0);
      }
    }
    __syncthreads();   // WAR: Vs/P/Ks[cur^1] reads done before next stage
  }

  // ---- epilogue ----
#pragma unroll
  for (int u = 0; u < 2; u++) {
    float linv = 1.0f / l_i[u];
    float lr[4];
#pragma unroll
    for (int r = 0; r < 4; r++) lr[r] = __shfl(linv, quad * 4 + r, 64);
#pragma unroll
    for (int r = 0; r < 4; r++) {
      int row = s0 + w * 32 + u * 16 + quad * 4 + r;
#pragma unroll
      for (int n = 0; n < 8; n++)
        attnb[((size_t)b * 2048 + row) * 2048 + h * 128 + n * 16 + lm] = f2b(oacc[u][n][r] * lr[r]);
    }
  }
}

// ---------------------------------------------------------------- launch ---
extern "C" void kernel_launch(void* const* d_in, const int* in_sizes, int n_in,
                              void* d_out, int out_size, void* d_ws, size_t ws_size,
                              hipStream_t stream) {
  const float* hs = (const float*)d_in[0];
  const float* Wq = (const float*)d_in[1];
  const float* Wk = (const float*)d_in[2];
  const float* Wv = (const float*)d_in[3];
  const float* Wo = (const float*)d_in[4];
  const float* kc = (const float*)d_in[5];
  const float* vc = (const float*)d_in[6];
  float* out = (float*)d_out;
  if (ws_size < (size_t)134217728) return;  // need 128 MiB

  char* ws = (char*)d_ws;
  u16* Xb  = (u16*)(ws);                 // 16 MiB (reused as attnb)
  u16* Wqb = (u16*)(ws + 16777216);      // stacked [Wq;Wk;Wv;Wo] bf16
  u16* Wob = Wqb + 12582912;
  u16* Kb  = (u16*)(ws + 50331648);      // [B,H,4096,128]
  u16* Vt  = (u16*)(ws + 83886080);      // [B,H,128,4096]
  u16* Qb  = (u16*)(ws + 117440512);     // [B,H,2048,128]
  u16* attnb = Xb;

  cast_all<<<dim3(4096, 8), 256, 0, stream>>>(hs, Wq, Wk, Wv, Wo, kc, Xb, Wqb, Kb);
  transpose_v<<<dim3(32, 32), 256, 0, stream>>>(vc, Vt);
  gemm_bt<<<dim3(48, 32), 256, 0, stream>>>(Xb, Wqb, Qb, Kb, Vt, nullptr, 0);
  attn_kernel<<<dim3(32, 16), 256, 0, stream>>>(Qb, Kb, Vt, attnb);
  gemm_bt<<<dim3(16, 32), 256, 0, stream>>>(attnb, Wob, nullptr, nullptr, nullptr, out, 1);
}